// Round 7
// baseline (3117.020 us; speedup 1.0000x reference)
//
#include <hip/hip_runtime.h>

// CharLSTM on MI355X — layer-pipelined persistent LSTM, round 7.
// R6 post-mortem: beat 13.7k cy ~= 4 serialized MALL round trips (publish drain,
// flag->poll observe, data load, x/bp chains) at ~2-3k cy each. R7 collapses
// sync to ONE round trip: sentinel protocol. |h|<1 strictly => f16 +inf 0x7C00
// is an impossible value; rings are poisoned with it, consumers speculatively
// load data and accept when poison-free (retry else). No produced flags, no
// publish drain. Slot recycling: producer poisons slot (t+1) at loop-top of t,
// drained before data(t) publishes (rides the x/h vmcnt(8) split) => acceptance
// of data(t) implies poison(t+1) visible => stale reads impossible.
// Everything else identical to passing R6.

typedef _Float16 f16;
typedef f16  f16x8 __attribute__((ext_vector_type(8)));
typedef f16  f16x4 __attribute__((ext_vector_type(4)));
typedef float f32x4 __attribute__((ext_vector_type(4)));
typedef int   i32x4 __attribute__((ext_vector_type(4)));

#define DEV __device__ __forceinline__

constexpr int TT = 512, BB = 64, VV = 100, HH = 256, LL = 8;
constexpr int RING_D = 32;
constexpr int POISON = 0x7C007C00;   // f16 +inf pair — impossible h value
constexpr int MAXRETRY = 4096;

// ---- workspace layout (bytes) ----
constexpr size_t XE_OFF = 0;
constexpr size_t XE_SZ  = (size_t)TT*BB*256*2;          // embedded x [T][B][256] f16
constexpr size_t WP_OFF = XE_OFF + XE_SZ;
constexpr size_t WP_SZ  = (size_t)LL*16*64*512*2;       // repacked W [L*16][64][512] f16
constexpr size_t BI_OFF = WP_OFF + WP_SZ;
constexpr size_t BI_SZ  = (size_t)LL*16*64*4;           // prescaled bias [L*16][64] f32
constexpr size_t FW_OFF = BI_OFF + BI_SZ;
constexpr size_t FW_SZ  = (size_t)112*256*2;            // fc_w padded
constexpr size_t H7_OFF = FW_OFF + FW_SZ;
constexpr size_t H7_SZ  = (size_t)TT*BB*256*2;          // layer-7 h history
constexpr size_t RG_OFF = H7_OFF + H7_SZ;
constexpr size_t RG_SZ  = (size_t)LL*RING_D*BB*256*2;   // rings [L][32][64][256] f16 (8MB)
constexpr size_t FCF_OFF = RG_OFF + RG_SZ;
constexpr size_t FCF_SZ  = (size_t)7*TT*16;             // x-consumed flags [l][T][sl] 1B/WG

// ---- agent-scope helpers ----
DEV void ld16_pl (i32x4& d, const void* p){ asm volatile("global_load_dwordx4 %0, %1, off"     : "=v"(d) : "v"(p)); }
DEV void ld16_sc1(i32x4& d, const void* p){ asm volatile("global_load_dwordx4 %0, %1, off sc1" : "=v"(d) : "v"(p)); }
DEV void st16_sc1(void* p, i32x4 d){ asm volatile("global_store_dwordx4 %0, %1, off sc1" :: "v"(p), "v"(d) : "memory"); }
DEV void stb_sc1(void* p){ unsigned o = 1; asm volatile("global_store_byte %0, %1, off sc1" :: "v"(p), "v"(o) : "memory"); }
DEV void wait_vm0(){ asm volatile("s_waitcnt vmcnt(0)" ::: "memory"); __builtin_amdgcn_sched_barrier(0); }
DEV void wait_vm8(){ asm volatile("s_waitcnt vmcnt(8)" ::: "memory"); __builtin_amdgcn_sched_barrier(0); }

// sentinel check: true = all 8x16B across all 64 lanes are poison-free
DEV bool chk8(const i32x4* f) {
  int bad = 0;
  #pragma unroll
  for (int i = 0; i < 8; ++i) {
    bad |= (f[i][0] == POISON);
    bad |= (f[i][1] == POISON);
    bad |= (f[i][2] == POISON);
    bad |= (f[i][3] == POISON);
  }
  return __all(bad == 0);
}

// backpressure poll: 16B line, uniform addr; usually hits first try (1-beat lookahead)
DEV bool poll16(const unsigned char* p) {
  for (int it = 0; it < (1 << 16); ++it) {
    i32x4 f;
    asm volatile("global_load_dwordx4 %0, %1, off sc1\n\ts_waitcnt vmcnt(0)"
                 : "=v"(f) : "v"(p) : "memory");
    if ((f[0] & f[1] & f[2] & f[3]) == 0x01010101) return true;
    if (it > 2) __builtin_amdgcn_s_sleep(1);
  }
  return false;
}

// gates prescaled by log2e (i,f,o) and 2*log2e (g) -> raw v_exp_f32
DEV float sig2(float y)  { return __builtin_amdgcn_rcpf(1.f + __builtin_amdgcn_exp2f(-y)); }
DEV float tanhp(float y) { return 1.f - 2.f * __builtin_amdgcn_rcpf(1.f + __builtin_amdgcn_exp2f(y)); }
constexpr float LOG2E = 1.4426950408889634f;
constexpr float C2LE  = 2.8853900817779268f;
DEV unsigned f16bits(float v) { f16 h = (f16)v; return (unsigned)__builtin_bit_cast(unsigned short, h); }

// =================== prep kernels ===================
__global__ void prep_zero(unsigned int* p) {       // grid 56x256 == 14336 dwords (fcf)
  p[blockIdx.x * 256 + threadIdx.x] = 0;
}
__global__ void prep_poison(unsigned int* p) {     // grid 2048x256, 16B/thread = rings 8MB
  size_t i = ((size_t)blockIdx.x * 256 + threadIdx.x) * 4;
  i32x4 P = {POISON, POISON, POISON, POISON};
  *(i32x4*)(p + i) = P;
}

__global__ void prep_embed(const int* __restrict__ x, const float* __restrict__ em,
                           f16* __restrict__ xe) {   // grid 1024x256
  int g = blockIdx.x * 256 + threadIdx.x;
  int chunk = g & 7, pair = g >> 3;
  int b = pair & 63, t = pair >> 6;
  int idx = x[b * 512 + t];
  const float* er = em + (size_t)idx * 100;
  f16* o = xe + (size_t)pair * 256 + chunk * 32;
  #pragma unroll
  for (int c4 = 0; c4 < 32; c4 += 4) {
    f16x4 v;
    #pragma unroll
    for (int q = 0; q < 4; ++q) {
      int c = chunk * 32 + c4 + q;
      v[q] = (c < 100) ? (f16)er[c] : (f16)0.f;
    }
    *(f16x4*)(o + c4) = v;
  }
}

// W row order per slice: n in [0,64): gate=n&3, u_local=(n>>4)*4+((n>>2)&3)
__global__ void prep_w(const float* __restrict__ w_ih0, const float* __restrict__ w_ih,
                       const float* __restrict__ w_hh, f16* __restrict__ wpo) { // grid 4096x256
  int g = blockIdx.x * 256 + threadIdx.x;
  int k4 = (g & 127) * 4;
  int n  = (g >> 7) & 63;
  int ls = g >> 13;
  int l = ls >> 4, s = ls & 15;
  int gate = n & 3;
  int u = s * 16 + ((n >> 4) << 2) + ((n >> 2) & 3);
  int r = 256 * gate + u;
  float scale = (gate == 2) ? C2LE : LOG2E;
  f16x4 v;
  #pragma unroll
  for (int q = 0; q < 4; ++q) {
    int k = k4 + q;
    float f;
    if (k < 256) {
      if (l == 0) f = (k < 100) ? w_ih0[(size_t)r * 100 + k] : 0.f;
      else        f = w_ih[((size_t)(l - 1) * 1024 + r) * 256 + k];
    } else        f = w_hh[((size_t)l * 1024 + r) * 256 + (k - 256)];
    v[q] = (f16)(f * scale);
  }
  *(f16x4*)(wpo + (size_t)g * 4) = v;
}

__global__ void prep_bias(const float* __restrict__ b_ih, const float* __restrict__ b_hh,
                          float* __restrict__ bo) {  // grid 32x256
  int g = blockIdx.x * 256 + threadIdx.x;
  int n = g & 63, s = (g >> 6) & 15, l = g >> 10;
  int gate = n & 3;
  int u = s * 16 + ((n >> 4) << 2) + ((n >> 2) & 3);
  int r = 256 * gate + u;
  float scale = (gate == 2) ? C2LE : LOG2E;
  bo[g] = (b_ih[l * 1024 + r] + b_hh[l * 1024 + r]) * scale;
}

__global__ void prep_fcw(const float* __restrict__ fc_w, f16* __restrict__ fo) { // grid 28x256
  int g = blockIdx.x * 256 + threadIdx.x;
  int n = g >> 6, k4 = (g & 63) * 4;
  f16x4 v;
  #pragma unroll
  for (int q = 0; q < 4; ++q)
    v[q] = (n < 100) ? (f16)fc_w[(size_t)n * 256 + k4 + q] : (f16)0.f;
  *(f16x4*)(fo + (size_t)g * 4) = v;
}

// =================== persistent pipeline kernel ===================
// WG(lyr = bx&7, sl = bx>>3): 64 gate-rows x 64 batch per beat, K=512.
// 8 waves: mA = wv>>2 (2 M-tiles), nB = wv&3 (16 batch cols).
// Beat: [wave0: bp-check + poison slot t+1] -> issue x,h loads -> vm8 ->
// check x (+retry) -> x-MFMAs -> vm0 -> check h (+retry) -> h-MFMAs -> gates
// -> LDS pub -> barrier -> wave0 publish (no drain, no flag).
__global__ void __launch_bounds__(512, 1) lstm_pipe(
    const f16* __restrict__ xe, const f16* __restrict__ wp, const float* __restrict__ biasp,
    f16* h7, f16* rings, unsigned char* fcf, float* out)
{
  __shared__ char pad_lds[40960];                  // + pub 6144 + dyn 35072 = 82176 -> 1 WG/CU
  __shared__ unsigned short pub[2][64][24];        // [parity][batch][16 units + pad]
  (void)((volatile char*)pad_lds)[threadIdx.x];

  const int bx  = blockIdx.x;
  const int lyr = bx & 7;                          // layer per XCD (perf heuristic)
  const int sl  = bx >> 3;                         // 16-unit slice
  const int tid = threadIdx.x;
  const int wv  = tid >> 6;
  const int ln  = tid & 63;
  const int mA  = wv >> 2;
  const int nB  = wv & 3;

  // ---- W fragments: 2 M-tiles x 16 K-tiles, register-resident ----
  f16x8 wfa[2][16];
  {
    const f16* wb = wp + (size_t)(lyr * 16 + sl) * 64 * 512;
    #pragma unroll
    for (int tt = 0; tt < 2; ++tt)
      #pragma unroll
      for (int kt = 0; kt < 16; ++kt) {
        wfa[tt][kt] = *(const f16x8*)(wb + (size_t)((2 * mA + tt) * 16 + (ln & 15)) * 512
                                      + kt * 32 + (ln >> 4) * 8);
        i32x4 pin = __builtin_bit_cast(i32x4, wfa[tt][kt]);
        asm volatile("" : "+v"(pin));              // freeze: no re-load inside loop
        wfa[tt][kt] = __builtin_bit_cast(f16x8, pin);
      }
  }
  f32x4 bias_v[2];
  #pragma unroll
  for (int tt = 0; tt < 2; ++tt) {
    bias_v[tt] = *(const f32x4*)(biasp + (size_t)(lyr * 16 + sl) * 64
                                 + (2 * mA + tt) * 16 + (ln >> 4) * 4);
    asm volatile("" : "+v"(bias_v[tt]));
  }

  float cst0 = 0.f, cst1 = 0.f;                    // cell state (2 units/lane)
  const int q    = ln >> 4;                        // 0..3
  const int bcol = nB * 16 + (ln & 15);            // batch col 0..63
  const int kof  = q * 8;
  const f16* xring = rings + (size_t)(lyr - 1) * RING_D * 16384;
  f16*       hring = rings + (size_t)lyr * RING_D * 16384;
  bool dead = false;

  for (int t = 0; t < TT; ++t) {
    // ---- wave0: backpressure (1-beat lookahead) + poison slot (t+1) ----
    if (wv == 0 && t + 1 < TT) {
      if (lyr < 7 && t + 1 >= RING_D && !dead)
        dead = !poll16(fcf + (size_t)(lyr * TT + (t + 1 - RING_D)) * 16);
      f16* pz = hring + (size_t)((t + 1) & (RING_D - 1)) * 16384
              + (size_t)ln * 256 + sl * 16;
      i32x4 P = {POISON, POISON, POISON, POISON};
      st16_sc1(pz, P);
      st16_sc1(pz + 8, P);
    }

    // ---- issue x loads then h loads ----
    const bool hasH = (t > 0);
    i32x4 bfx[8], bfh[8];
    {
      const f16* xb = ((lyr == 0) ? xe + (size_t)t * 16384
                                  : xring + (size_t)(t & (RING_D - 1)) * 16384)
                      + (size_t)bcol * 256 + kof;
      if (lyr == 0) {
        #pragma unroll
        for (int kt = 0; kt < 8; ++kt) ld16_pl(bfx[kt], xb + kt * 32);
      } else {
        #pragma unroll
        for (int kt = 0; kt < 8; ++kt) ld16_sc1(bfx[kt], xb + kt * 32);
      }
      if (hasH) {
        const f16* hb = hring + (size_t)((t - 1) & (RING_D - 1)) * 16384
                      + (size_t)bcol * 256 + kof;
        #pragma unroll
        for (int kt = 0; kt < 8; ++kt) ld16_sc1(bfh[kt], hb + kt * 32);
      }
    }
    // vm8: x (and poison, and last beat's publish) drained; h still in flight
    if (hasH) wait_vm8(); else wait_vm0();

    // ---- x acceptance (rare retry; steady state: producer is a beat ahead) ----
    if (lyr > 0 && !dead) {
      int it = 0;
      while (!chk8(bfx)) {
        if (++it > MAXRETRY) { dead = true; break; }
        wait_vm0();                                // drain h too (slow path)
        const f16* xb = xring + (size_t)(t & (RING_D - 1)) * 16384
                      + (size_t)bcol * 256 + kof;
        #pragma unroll
        for (int kt = 0; kt < 8; ++kt) ld16_sc1(bfx[kt], xb + kt * 32);
        wait_vm0();
      }
    }

    // ---- x-MFMAs (h loads still flying) ----
    f32x4 acc0 = {0,0,0,0}, acc1 = {0,0,0,0};
    #pragma unroll
    for (int kt = 0; kt < 8; ++kt) {
      f16x8 av = __builtin_bit_cast(f16x8, bfx[kt]);
      acc0 = __builtin_amdgcn_mfma_f32_16x16x32_f16(wfa[0][kt], av, acc0, 0, 0, 0);
      acc1 = __builtin_amdgcn_mfma_f32_16x16x32_f16(wfa[1][kt], av, acc1, 0, 0, 0);
    }

    // ---- h acceptance + h-MFMAs ----
    if (hasH) {
      wait_vm0();
      if (!dead) {
        int it = 0;
        while (!chk8(bfh)) {
          if (++it > MAXRETRY) { dead = true; break; }
          const f16* hb = hring + (size_t)((t - 1) & (RING_D - 1)) * 16384
                        + (size_t)bcol * 256 + kof;
          #pragma unroll
          for (int kt = 0; kt < 8; ++kt) ld16_sc1(bfh[kt], hb + kt * 32);
          wait_vm0();
        }
      }
      #pragma unroll
      for (int kt = 0; kt < 8; ++kt) {
        f16x8 av = __builtin_bit_cast(f16x8, bfh[kt]);
        acc0 = __builtin_amdgcn_mfma_f32_16x16x32_f16(wfa[0][8 + kt], av, acc0, 0, 0, 0);
        acc1 = __builtin_amdgcn_mfma_f32_16x16x32_f16(wfa[1][8 + kt], av, acc1, 0, 0, 0);
      }
    }

    // ---- gates in-register; h -> LDS transpose buffer ----
    const int par = t & 1;
    #pragma unroll
    for (int tt = 0; tt < 2; ++tt) {
      f32x4 g4 = (tt == 0 ? acc0 : acc1);
      g4 += bias_v[tt];
      float i_ = sig2(g4[0]), f_ = sig2(g4[1]), z_ = tanhp(g4[2]), o_ = sig2(g4[3]);
      float& c_ = (tt == 0 ? cst0 : cst1);
      c_ = f_ * c_ + i_ * z_;
      float h_ = o_ * tanhp(c_ * C2LE);
      pub[par][bcol][(2 * mA + tt) * 4 + q] = (unsigned short)f16bits(h_);
      if (t == TT - 1) {
        const int u = sl * 16 + (2 * mA + tt) * 4 + q;
        size_t ob = 3276800 + (size_t)lyr * 16384 + (size_t)bcol * 256 + u;
        out[ob] = h_;  out[ob + 131072] = c_;
      }
    }
    __syncthreads();                               // single barrier per beat

    // ---- publish: wave0, 32B/lane contiguous, NO drain, NO flag ----
    if (wv == 0) {
      i32x4 d0 = *(const i32x4*)&pub[par][ln][0];
      i32x4 d1 = *(const i32x4*)&pub[par][ln][8];
      f16* dst = hring + (size_t)(t & (RING_D - 1)) * 16384 + (size_t)ln * 256 + sl * 16;
      st16_sc1(dst, d0);
      st16_sc1(dst + 8, d1);
      if (lyr == 7) {
        f16* hd = h7 + (size_t)t * 16384 + (size_t)ln * 256 + sl * 16;
        *(i32x4*)hd = d0;
        *(i32x4*)(hd + 8) = d1;
      }
      if (ln == 1 && lyr > 0)                      // x slot t consumed (for producer's bp)
        stb_sc1(fcf + (size_t)((lyr - 1) * TT + t) * 16 + sl);
    }
  }
}

// =================== final FC ===================
__global__ void __launch_bounds__(256, 1) fc_kernel(
    const f16* __restrict__ h7, const f16* __restrict__ fcw,
    const float* __restrict__ fcb, float* __restrict__ out)
{
  const int t  = blockIdx.x;
  const int wv = threadIdx.x >> 6;
  const int ln = threadIdx.x & 63;
  const f16* ab = h7 + (size_t)t * 16384 + (size_t)(wv * 16 + (ln & 15)) * 256 + (ln >> 4) * 8;
  f16x8 af[8];
  #pragma unroll
  for (int kt = 0; kt < 8; ++kt) af[kt] = *(const f16x8*)(ab + kt * 32);
  const int obrow = wv * 16 + (ln >> 4) * 4;
  #pragma unroll
  for (int nt = 0; nt < 7; ++nt) {
    const f16* bb = fcw + (size_t)(nt * 16 + (ln & 15)) * 256 + (ln >> 4) * 8;
    f32x4 acc = {0, 0, 0, 0};
    #pragma unroll
    for (int kt = 0; kt < 8; ++kt) {
      f16x8 bv = *(const f16x8*)(bb + kt * 32);
      acc = __builtin_amdgcn_mfma_f32_16x16x32_f16(af[kt], bv, acc, 0, 0, 0);
    }
    int vg = nt * 16 + (ln & 15);
    if (vg < VV) {
      float bias = fcb[vg];
      #pragma unroll
      for (int j = 0; j < 4; ++j)
        out[(size_t)(obrow + j) * 51200 + (size_t)t * 100 + vg] = acc[j] + bias;
    }
  }
}

// =================== launch ===================
extern "C" void kernel_launch(void* const* d_in, const int* in_sizes, int n_in,
                              void* d_out, int out_size, void* d_ws, size_t ws_size,
                              hipStream_t stream) {
  (void)in_sizes; (void)n_in; (void)out_size; (void)ws_size;
  const int*   x     = (const int*)d_in[0];
  const float* embed = (const float*)d_in[1];
  const float* w_ih0 = (const float*)d_in[2];
  const float* w_ih  = (const float*)d_in[3];
  const float* w_hh  = (const float*)d_in[4];
  const float* b_ih  = (const float*)d_in[5];
  const float* b_hh  = (const float*)d_in[6];
  const float* fc_w  = (const float*)d_in[7];
  const float* fc_b  = (const float*)d_in[8];
  char* ws = (char*)d_ws;
  float* out = (float*)d_out;

  // per-call re-init: consumed flags zeroed, rings poisoned
  prep_zero<<<56, 256, 0, stream>>>((unsigned int*)(ws + FCF_OFF));
  prep_poison<<<2048, 256, 0, stream>>>((unsigned int*)(ws + RG_OFF));
  prep_embed<<<1024, 256, 0, stream>>>(x, embed, (f16*)(ws + XE_OFF));
  prep_w<<<4096, 256, 0, stream>>>(w_ih0, w_ih, w_hh, (f16*)(ws + WP_OFF));
  prep_bias<<<32, 256, 0, stream>>>(b_ih, b_hh, (float*)(ws + BI_OFF));
  prep_fcw<<<28, 256, 0, stream>>>(fc_w, (f16*)(ws + FW_OFF));

  // static LDS 47104 + dynamic 35072 = 82176 B > 80 KiB -> 1 WG/CU
  lstm_pipe<<<128, 512, 35072, stream>>>(
      (const f16*)(ws + XE_OFF), (const f16*)(ws + WP_OFF), (const float*)(ws + BI_OFF),
      (f16*)(ws + H7_OFF), (f16*)(ws + RG_OFF),
      (unsigned char*)(ws + FCF_OFF), out);

  fc_kernel<<<512, 256, 0, stream>>>((const f16*)(ws + H7_OFF), (const f16*)(ws + FW_OFF),
                                     fc_b, out);
}